// Round 1
// baseline (968.179 us; speedup 1.0000x reference)
//
#include <hip/hip_runtime.h>

#define DEV __device__ __forceinline__

typedef __attribute__((ext_vector_type(8))) short sh8;
typedef __attribute__((ext_vector_type(4))) float f32x4;

DEV ushort f2bf(float f) {
  union { float f; unsigned u; } v; v.f = f;
  unsigned r = v.u + 0x7FFFu + ((v.u >> 16) & 1u);
  return (ushort)(r >> 16);
}
DEV float bf2f(ushort h) {
  union { unsigned u; float f; } v; v.u = ((unsigned)h) << 16;
  return v.f;
}
DEV float sigmoidf_(float x) { return 1.f / (1.f + __expf(-x)); }

// ---------------- cast f32 -> bf16 ----------------
__global__ __launch_bounds__(256) void cast_bf_kernel(const float* __restrict__ src,
                                                      ushort* __restrict__ dst, int n) {
  int i = blockIdx.x * 256 + threadIdx.x;
  if (i < n) dst[i] = f2bf(src[i]);
}

// ---------------- layernorm (per token) -> bf16 ----------------
__global__ __launch_bounds__(256) void ln_kernel(const float* __restrict__ x,
    const float* __restrict__ g, const float* __restrict__ b, ushort* __restrict__ xn) {
  const int t = blockIdx.x;
  const int tid = threadIdx.x;
  const float* row = x + (size_t)t * 1024;
  float4 v = reinterpret_cast<const float4*>(row)[tid];
  float s1 = v.x + v.y + v.z + v.w;
  float s2 = v.x * v.x + v.y * v.y + v.z * v.z + v.w * v.w;
  for (int off = 32; off >= 1; off >>= 1) {
    s1 += __shfl_xor(s1, off);
    s2 += __shfl_xor(s2, off);
  }
  __shared__ float red[8];
  int w = tid >> 6, lane = tid & 63;
  if (lane == 0) { red[w] = s1; red[4 + w] = s2; }
  __syncthreads();
  s1 = red[0] + red[1] + red[2] + red[3];
  s2 = red[4] + red[5] + red[6] + red[7];
  float mu = s1 * (1.f / 1024.f);
  float var = s2 * (1.f / 1024.f) - mu * mu;
  float rstd = rsqrtf(var + 1e-5f);
  float4 gv = reinterpret_cast<const float4*>(g)[tid];
  float4 bv = reinterpret_cast<const float4*>(b)[tid];
  ushort o[4];
  o[0] = f2bf((v.x - mu) * rstd * gv.x + bv.x);
  o[1] = f2bf((v.y - mu) * rstd * gv.y + bv.y);
  o[2] = f2bf((v.z - mu) * rstd * gv.z + bv.z);
  o[3] = f2bf((v.w - mu) * rstd * gv.w + bv.w);
  *reinterpret_cast<ushort4*>(&xn[(size_t)t * 1024 + tid * 4]) = *reinterpret_cast<ushort4*>(o);
}

// ---------------- generic bf16 MFMA GEMM, 128x128 tile, 4 waves ----------------
// EPI 0: C(4096 cols) split -> ob0=xb_bf16 (n<2048), ob1=z_bf16
// EPI 1: of0=dbc f32 (n<96), ob0=dtraw bf16 (n<64)
// EPI 2: of0=dt bf16 via ob0 = softplus(acc + aux[n])
// EPI 3: of0=out f32 = acc + aux[m*1024+n]  (residual)
template <int EPI>
__global__ __launch_bounds__(256)
void gemm_bf16(const ushort* __restrict__ A, int lda,
               const ushort* __restrict__ B, int ldb,
               int K, int Nreal,
               float* __restrict__ of0,
               ushort* __restrict__ ob0, ushort* __restrict__ ob1,
               const float* __restrict__ aux) {
  __shared__ ushort As[128 * 40];
  __shared__ ushort Bs[128 * 40];
  const int tid = threadIdx.x;
  const int lane = tid & 63;
  const int w = tid >> 6;
  const int wm = w >> 1, wn = w & 1;
  const int m0 = blockIdx.x * 128;
  const int n0 = blockIdx.y * 128;
  const int row16 = lane & 15;
  const int g = lane >> 4;

  f32x4 acc[4][4];
#pragma unroll
  for (int i = 0; i < 4; ++i)
#pragma unroll
    for (int j = 0; j < 4; ++j) acc[i][j] = f32x4{0.f, 0.f, 0.f, 0.f};

  const int ar = tid >> 1;
  const int ac = (tid & 1) * 16;
  const int br = tid >> 3;
  const int bc = (tid & 7) * 16;

  for (int kk = 0; kk < K; kk += 32) {
    // stage A tile [128][32] row-major, pad stride 40
    {
      const ushort* src = A + (size_t)(m0 + ar) * lda + kk + ac;
      sh8 v0 = *reinterpret_cast<const sh8*>(src);
      sh8 v1 = *reinterpret_cast<const sh8*>(src + 8);
      *reinterpret_cast<sh8*>(&As[ar * 40 + ac]) = v0;
      *reinterpret_cast<sh8*>(&As[ar * 40 + ac + 8]) = v1;
    }
    // stage B tile transposed: Bs[col][row], pad stride 40
    {
      const ushort* src = B + (size_t)(kk + br) * ldb + n0 + bc;
      if (n0 + bc + 15 < Nreal) {
        sh8 v0 = *reinterpret_cast<const sh8*>(src);
        sh8 v1 = *reinterpret_cast<const sh8*>(src + 8);
#pragma unroll
        for (int j = 0; j < 8; ++j) {
          Bs[(bc + j) * 40 + br] = (ushort)v0[j];
          Bs[(bc + 8 + j) * 40 + br] = (ushort)v1[j];
        }
      } else {
#pragma unroll
        for (int j = 0; j < 16; ++j) {
          ushort vv = (n0 + bc + j < Nreal) ? src[j] : (ushort)0;
          Bs[(bc + j) * 40 + br] = vv;
        }
      }
    }
    __syncthreads();
    sh8 af[4], bfr[4];
#pragma unroll
    for (int i = 0; i < 4; ++i) {
      af[i]  = *reinterpret_cast<const sh8*>(&As[(wm * 64 + i * 16 + row16) * 40 + g * 8]);
      bfr[i] = *reinterpret_cast<const sh8*>(&Bs[(wn * 64 + i * 16 + row16) * 40 + g * 8]);
    }
#pragma unroll
    for (int mi = 0; mi < 4; ++mi)
#pragma unroll
      for (int ni = 0; ni < 4; ++ni)
        acc[mi][ni] = __builtin_amdgcn_mfma_f32_16x16x32_bf16(af[mi], bfr[ni], acc[mi][ni], 0, 0, 0);
    __syncthreads();
  }

#pragma unroll
  for (int mi = 0; mi < 4; ++mi) {
#pragma unroll
    for (int ni = 0; ni < 4; ++ni) {
#pragma unroll
      for (int j = 0; j < 4; ++j) {
        int m = m0 + wm * 64 + mi * 16 + g * 4 + j;
        int n = n0 + wn * 64 + ni * 16 + row16;
        float v = acc[mi][ni][j];
        if (EPI == 0) {
          ushort bvv = f2bf(v);
          if (n < 2048) ob0[(size_t)m * 2048 + n] = bvv;
          else          ob1[(size_t)m * 2048 + (n - 2048)] = bvv;
        } else if (EPI == 1) {
          if (n < Nreal) {
            of0[(size_t)m * 96 + n] = v;
            if (n < 64) ob0[(size_t)m * 64 + n] = f2bf(v);
          }
        } else if (EPI == 2) {
          float tpre = v + aux[n];
          float sp = (tpre > 20.f) ? tpre : log1pf(__expf(tpre));
          ob0[(size_t)m * 2048 + n] = f2bf(sp);
        } else {
          of0[(size_t)m * 1024 + n] = v + aux[(size_t)m * 1024 + n];
        }
      }
    }
  }
}

// ---------------- depthwise causal conv (width 4) + SiLU -> bf16 ----------------
__global__ __launch_bounds__(256) void conv_silu_kernel(const ushort* __restrict__ xb,
    const float* __restrict__ cw, const float* __restrict__ cb, ushort* __restrict__ u) {
  long long idx = (long long)blockIdx.x * 256 + threadIdx.x;  // over B*L*D = 8388608
  int d = (int)(idx & 2047);
  int t = (int)((idx >> 11) & 2047);
  float acc = cb[d];
  float4 w4 = reinterpret_cast<const float4*>(cw)[d];
  float wj[4] = {w4.x, w4.y, w4.z, w4.w};
#pragma unroll
  for (int j = 0; j < 4; ++j) {
    int tt = t - 3 + j;
    if (tt >= 0) acc += bf2f(xb[idx + (long long)(j - 3) * 2048]) * wj[j];
  }
  u[idx] = f2bf(acc * sigmoidf_(acc));
}

// ---------------- selective scan + fused gate ----------------
// lane = (d_sub, s): 4 d per wave, 16 states; 16 d per block; 256 blocks.
// writes yg = (scan_y + u*D) * silu(z) as bf16 IN PLACE over u.
__global__ __launch_bounds__(256) void scan_kernel(
    const ushort* __restrict__ dt, ushort* __restrict__ u_io,
    const float* __restrict__ dbc, const float* __restrict__ A_log,
    const float* __restrict__ Dp, const ushort* __restrict__ zb) {
  __shared__ float dt_s[64][16], u_s[64][16], B_s[64][16], C_s[64][16], y_s[64][16];
  const int tid = threadIdx.x;
  const int lane = tid & 63;
  const int w = tid >> 6;
  const int s = lane & 15;
  const int dloc = w * 4 + (lane >> 4);
  const int batch = blockIdx.x >> 7;
  const int d0 = (blockIdx.x & 127) * 16;
  const int d = d0 + dloc;
  const float Aval = -__expf(A_log[d * 16 + s]);
  const float Dval = Dp[d];
  float h = 0.f;
  const size_t base = (size_t)batch * 2048 * 2048;
  const size_t bbase = (size_t)batch * 2048 * 96;
  for (int tc = 0; tc < 2048; tc += 64) {
    for (int i = tid; i < 1024; i += 256) {
      int tt = i >> 4, di = i & 15;
      int t = tc + tt;
      size_t gidx = base + (size_t)t * 2048 + d0 + di;
      dt_s[tt][di] = bf2f(dt[gidx]);
      u_s[tt][di] = bf2f(u_io[gidx]);
      size_t bidx = bbase + (size_t)t * 96;
      B_s[tt][di] = dbc[bidx + 64 + di];
      C_s[tt][di] = dbc[bidx + 80 + di];
    }
    __syncthreads();
#pragma unroll 4
    for (int tt = 0; tt < 64; ++tt) {
      float dtv = dt_s[tt][dloc];
      float uv = u_s[tt][dloc];
      float dA = __expf(dtv * Aval);
      h = dA * h + (dtv * uv) * B_s[tt][s];
      float p = h * C_s[tt][s];
      p += __shfl_xor(p, 1);
      p += __shfl_xor(p, 2);
      p += __shfl_xor(p, 4);
      p += __shfl_xor(p, 8);
      if (s == 0) y_s[tt][dloc] = p + uv * Dval;
    }
    __syncthreads();
    for (int i = tid; i < 1024; i += 256) {
      int tt = i >> 4, di = i & 15;
      size_t gidx = base + (size_t)(tc + tt) * 2048 + d0 + di;
      float zv = bf2f(zb[gidx]);
      float yv = y_s[tt][di];
      u_io[gidx] = f2bf(yv * zv * sigmoidf_(zv));
    }
    __syncthreads();
  }
}

extern "C" void kernel_launch(void* const* d_in, const int* in_sizes, int n_in,
                              void* d_out, int out_size, void* d_ws, size_t ws_size,
                              hipStream_t stream) {
  const float* x      = (const float*)d_in[0];
  const float* ln_g   = (const float*)d_in[1];
  const float* ln_b   = (const float*)d_in[2];
  const float* W_in   = (const float*)d_in[3];
  const float* conv_w = (const float*)d_in[4];
  const float* conv_b = (const float*)d_in[5];
  const float* W_x    = (const float*)d_in[6];
  const float* W_dt   = (const float*)d_in[7];
  const float* b_dt   = (const float*)d_in[8];
  const float* A_log  = (const float*)d_in[9];
  const float* D_par  = (const float*)d_in[10];
  const float* W_out  = (const float*)d_in[11];
  float* out = (float*)d_out;
  (void)in_sizes; (void)n_in; (void)out_size; (void)ws_size;

  char* ws = (char*)d_ws;
  size_t off = 0;
  auto alloc = [&](size_t bytes) -> void* {
    void* p = ws + off;
    off += (bytes + 255) & ~(size_t)255;
    return p;
  };
  ushort* xn    = (ushort*)alloc(4096ull * 1024 * 2);  // LN out (bf16)
  ushort* Winb  = (ushort*)alloc(1024ull * 4096 * 2);
  ushort* xbb   = (ushort*)alloc(4096ull * 2048 * 2);  // conv input (bf16)
  ushort* zbb   = (ushort*)alloc(4096ull * 2048 * 2);  // gate input (bf16)
  ushort* ub    = (ushort*)alloc(4096ull * 2048 * 2);  // u (bf16); scan overwrites with yg
  ushort* Wxb   = (ushort*)alloc(2048ull * 96 * 2);
  float*  dbc   = (float*) alloc(4096ull * 96 * 4);
  ushort* dtr   = (ushort*)alloc(4096ull * 64 * 2);
  ushort* Wdtb  = (ushort*)alloc(64ull * 2048 * 2);
  ushort* dtb   = (ushort*)alloc(4096ull * 2048 * 2);  // softplus(dt) bf16
  ushort* Woutb = (ushort*)alloc(2048ull * 1024 * 2);

  // weight casts
  cast_bf_kernel<<<dim3(1024 * 4096 / 256), 256, 0, stream>>>(W_in, Winb, 1024 * 4096);
  cast_bf_kernel<<<dim3(2048 * 96 / 256), 256, 0, stream>>>(W_x, Wxb, 2048 * 96);
  cast_bf_kernel<<<dim3(64 * 2048 / 256), 256, 0, stream>>>(W_dt, Wdtb, 64 * 2048);
  cast_bf_kernel<<<dim3(2048 * 1024 / 256), 256, 0, stream>>>(W_out, Woutb, 2048 * 1024);

  // layernorm
  ln_kernel<<<dim3(4096), 256, 0, stream>>>(x, ln_g, ln_b, xn);

  // xz = xn @ W_in  -> xb_bf16, z_bf16
  gemm_bf16<0><<<dim3(32, 32), 256, 0, stream>>>(xn, 1024, Winb, 4096, 1024, 4096,
                                                 nullptr, xbb, zbb, nullptr);

  // depthwise conv + silu -> u (bf16)
  conv_silu_kernel<<<dim3(8388608 / 256), 256, 0, stream>>>(xbb, conv_w, conv_b, ub);

  // dbc = u @ W_x  (N=96 in a 128 tile)
  gemm_bf16<1><<<dim3(32, 1), 256, 0, stream>>>(ub, 2048, Wxb, 96, 2048, 96,
                                                dbc, dtr, nullptr, nullptr);

  // dt = softplus(dtraw @ W_dt + b_dt) -> bf16
  gemm_bf16<2><<<dim3(32, 16), 256, 0, stream>>>(dtr, 64, Wdtb, 2048, 64, 2048,
                                                 nullptr, dtb, nullptr, b_dt);

  // selective scan + fused (y + u*D) * silu(z) -> yg (in place over u buffer)
  scan_kernel<<<dim3(256), 256, 0, stream>>>(dtb, ub, dbc, A_log, D_par, zbb);

  // out = x + yg @ W_out
  gemm_bf16<3><<<dim3(32, 8), 256, 0, stream>>>(ub, 2048, Woutb, 1024, 2048, 1024,
                                                out, nullptr, nullptr, x);
}

// Round 3
// 606.531 us; speedup vs baseline: 1.5963x; 1.5963x over previous
//
#include <hip/hip_runtime.h>

#define DEV __device__ __forceinline__

typedef __attribute__((ext_vector_type(8))) short sh8;
typedef __attribute__((ext_vector_type(4))) float f32x4;

DEV ushort f2bf(float f) {
  union { float f; unsigned u; } v; v.f = f;
  unsigned r = v.u + 0x7FFFu + ((v.u >> 16) & 1u);
  return (ushort)(r >> 16);
}
DEV float bf2f(ushort h) {
  union { unsigned u; float f; } v; v.u = ((unsigned)h) << 16;
  return v.f;
}
DEV float sigmoidf_(float x) { return 1.f / (1.f + __expf(-x)); }

// ---------------- cast f32 -> bf16 ----------------
__global__ __launch_bounds__(256) void cast_bf_kernel(const float* __restrict__ src,
                                                      ushort* __restrict__ dst, int n) {
  int i = blockIdx.x * 256 + threadIdx.x;
  if (i < n) dst[i] = f2bf(src[i]);
}

// ---------------- layernorm (per token) -> bf16 ----------------
__global__ __launch_bounds__(256) void ln_kernel(const float* __restrict__ x,
    const float* __restrict__ g, const float* __restrict__ b, ushort* __restrict__ xn) {
  const int t = blockIdx.x;
  const int tid = threadIdx.x;
  const float* row = x + (size_t)t * 1024;
  float4 v = reinterpret_cast<const float4*>(row)[tid];
  float s1 = v.x + v.y + v.z + v.w;
  float s2 = v.x * v.x + v.y * v.y + v.z * v.z + v.w * v.w;
  for (int off = 32; off >= 1; off >>= 1) {
    s1 += __shfl_xor(s1, off);
    s2 += __shfl_xor(s2, off);
  }
  __shared__ float red[8];
  int w = tid >> 6, lane = tid & 63;
  if (lane == 0) { red[w] = s1; red[4 + w] = s2; }
  __syncthreads();
  s1 = red[0] + red[1] + red[2] + red[3];
  s2 = red[4] + red[5] + red[6] + red[7];
  float mu = s1 * (1.f / 1024.f);
  float var = s2 * (1.f / 1024.f) - mu * mu;
  float rstd = rsqrtf(var + 1e-5f);
  float4 gv = reinterpret_cast<const float4*>(g)[tid];
  float4 bv = reinterpret_cast<const float4*>(b)[tid];
  ushort o[4];
  o[0] = f2bf((v.x - mu) * rstd * gv.x + bv.x);
  o[1] = f2bf((v.y - mu) * rstd * gv.y + bv.y);
  o[2] = f2bf((v.z - mu) * rstd * gv.z + bv.z);
  o[3] = f2bf((v.w - mu) * rstd * gv.w + bv.w);
  *reinterpret_cast<ushort4*>(&xn[(size_t)t * 1024 + tid * 4]) = *reinterpret_cast<ushort4*>(o);
}

// ---------------- generic bf16 MFMA GEMM, 128x128 tile, 4 waves ----------------
template <int EPI>
__global__ __launch_bounds__(256)
void gemm_bf16(const ushort* __restrict__ A, int lda,
               const ushort* __restrict__ B, int ldb,
               int K, int Nreal,
               float* __restrict__ of0,
               ushort* __restrict__ ob0, ushort* __restrict__ ob1,
               const float* __restrict__ aux) {
  __shared__ ushort As[128 * 40];
  __shared__ ushort Bs[128 * 40];
  const int tid = threadIdx.x;
  const int lane = tid & 63;
  const int w = tid >> 6;
  const int wm = w >> 1, wn = w & 1;
  const int m0 = blockIdx.x * 128;
  const int n0 = blockIdx.y * 128;
  const int row16 = lane & 15;
  const int g = lane >> 4;

  f32x4 acc[4][4];
#pragma unroll
  for (int i = 0; i < 4; ++i)
#pragma unroll
    for (int j = 0; j < 4; ++j) acc[i][j] = f32x4{0.f, 0.f, 0.f, 0.f};

  const int ar = tid >> 1;
  const int ac = (tid & 1) * 16;
  const int br = tid >> 3;
  const int bc = (tid & 7) * 16;

  for (int kk = 0; kk < K; kk += 32) {
    {
      const ushort* src = A + (size_t)(m0 + ar) * lda + kk + ac;
      sh8 v0 = *reinterpret_cast<const sh8*>(src);
      sh8 v1 = *reinterpret_cast<const sh8*>(src + 8);
      *reinterpret_cast<sh8*>(&As[ar * 40 + ac]) = v0;
      *reinterpret_cast<sh8*>(&As[ar * 40 + ac + 8]) = v1;
    }
    {
      const ushort* src = B + (size_t)(kk + br) * ldb + n0 + bc;
      if (n0 + bc + 15 < Nreal) {
        sh8 v0 = *reinterpret_cast<const sh8*>(src);
        sh8 v1 = *reinterpret_cast<const sh8*>(src + 8);
#pragma unroll
        for (int j = 0; j < 8; ++j) {
          Bs[(bc + j) * 40 + br] = (ushort)v0[j];
          Bs[(bc + 8 + j) * 40 + br] = (ushort)v1[j];
        }
      } else {
#pragma unroll
        for (int j = 0; j < 16; ++j) {
          ushort vv = (n0 + bc + j < Nreal) ? src[j] : (ushort)0;
          Bs[(bc + j) * 40 + br] = vv;
        }
      }
    }
    __syncthreads();
    sh8 af[4], bfr[4];
#pragma unroll
    for (int i = 0; i < 4; ++i) {
      af[i]  = *reinterpret_cast<const sh8*>(&As[(wm * 64 + i * 16 + row16) * 40 + g * 8]);
      bfr[i] = *reinterpret_cast<const sh8*>(&Bs[(wn * 64 + i * 16 + row16) * 40 + g * 8]);
    }
#pragma unroll
    for (int mi = 0; mi < 4; ++mi)
#pragma unroll
      for (int ni = 0; ni < 4; ++ni)
        acc[mi][ni] = __builtin_amdgcn_mfma_f32_16x16x32_bf16(af[mi], bfr[ni], acc[mi][ni], 0, 0, 0);
    __syncthreads();
  }

#pragma unroll
  for (int mi = 0; mi < 4; ++mi) {
#pragma unroll
    for (int ni = 0; ni < 4; ++ni) {
#pragma unroll
      for (int j = 0; j < 4; ++j) {
        int m = m0 + wm * 64 + mi * 16 + g * 4 + j;
        int n = n0 + wn * 64 + ni * 16 + row16;
        float v = acc[mi][ni][j];
        if (EPI == 0) {
          ushort bvv = f2bf(v);
          if (n < 2048) ob0[(size_t)m * 2048 + n] = bvv;
          else          ob1[(size_t)m * 2048 + (n - 2048)] = bvv;
        } else if (EPI == 1) {
          if (n < Nreal) {
            of0[(size_t)m * 96 + n] = v;
            if (n < 64) ob0[(size_t)m * 64 + n] = f2bf(v);
          }
        } else if (EPI == 2) {
          float tpre = v + aux[n];
          float sp = (tpre > 20.f) ? tpre : log1pf(__expf(tpre));
          ob0[(size_t)m * 2048 + n] = f2bf(sp);
        } else {
          of0[(size_t)m * 1024 + n] = v + aux[(size_t)m * 1024 + n];
        }
      }
    }
  }
}

// ---------------- depthwise causal conv (width 4) + SiLU -> bf16 ----------------
__global__ __launch_bounds__(256) void conv_silu_kernel(const ushort* __restrict__ xb,
    const float* __restrict__ cw, const float* __restrict__ cb, ushort* __restrict__ u) {
  long long idx = (long long)blockIdx.x * 256 + threadIdx.x;
  int d = (int)(idx & 2047);
  int t = (int)((idx >> 11) & 2047);
  float acc = cb[d];
  float4 w4 = reinterpret_cast<const float4*>(cw)[d];
  float wj[4] = {w4.x, w4.y, w4.z, w4.w};
#pragma unroll
  for (int j = 0; j < 4; ++j) {
    int tt = t - 3 + j;
    if (tt >= 0) acc += bf2f(xb[idx + (long long)(j - 3) * 2048]) * wj[j];
  }
  u[idx] = f2bf(acc * sigmoidf_(acc));
}

// ================= chunked selective scan: 3 passes =================
// Pass 1: per-chunk (prod dA, h_end | h0=0)
__global__ __launch_bounds__(256) void scan_p1(
    const ushort* __restrict__ dt, const ushort* __restrict__ u,
    const float* __restrict__ dbc, const float* __restrict__ A_log,
    float* __restrict__ Aprod, float* __restrict__ hEnd) {
  __shared__ float B_s[64][16];
  const int tid = threadIdx.x;
  const int bx = blockIdx.x;
  const int db = bx & 7, c = (bx >> 3) & 31, b = bx >> 8;
  const int d = db * 256 + tid;
  const int t0 = c * 64;
  for (int i = tid; i < 1024; i += 256) {
    int t = i >> 4, s = i & 15;
    B_s[t][s] = dbc[((size_t)(b * 2048 + t0 + t)) * 96 + 64 + s];
  }
  float A2[16], h[16], a[16];
  const float* Arow = A_log + d * 16;
#pragma unroll
  for (int s = 0; s < 16; ++s) {
    A2[s] = -__expf(Arow[s]) * 1.44269504088896f;
    h[s] = 0.f; a[s] = 1.f;
  }
  __syncthreads();
  const size_t base = (size_t)(b * 2048 + t0) * 2048 + d;
#pragma unroll 4
  for (int t = 0; t < 64; ++t) {
    float dtv = bf2f(dt[base + (size_t)t * 2048]);
    float uv  = bf2f(u[base + (size_t)t * 2048]);
    float x = dtv * uv;
#pragma unroll
    for (int s = 0; s < 16; ++s) {
      float e = exp2f(dtv * A2[s]);
      a[s] *= e;
      h[s] = e * h[s] + x * B_s[t][s];
    }
  }
  const size_t o = ((size_t)(b * 32 + c) * 2048 + d) * 16;
#pragma unroll
  for (int s = 0; s < 16; s += 4) {
    *reinterpret_cast<float4*>(&Aprod[o + s]) = make_float4(a[s], a[s+1], a[s+2], a[s+3]);
    *reinterpret_cast<float4*>(&hEnd[o + s])  = make_float4(h[s], h[s+1], h[s+2], h[s+3]);
  }
}

// Pass 2: chunk-prefix. Overwrites Aprod with Hstart.
__global__ __launch_bounds__(256) void scan_p2(
    float* __restrict__ Aprod, const float* __restrict__ hEnd) {
  const int i = blockIdx.x * 256 + threadIdx.x;
  const int b = i >> 15, ds = i & 32767;
  float H = 0.f;
  for (int c = 0; c < 32; ++c) {
    size_t idx = ((size_t)(b * 32 + c)) * 32768 + ds;
    float aP = Aprod[idx];
    float hE = hEnd[idx];
    Aprod[idx] = H;
    H = aP * H + hE;
  }
}

// Pass 3: re-scan with true Hstart; fused gate; writes yg over u.
__global__ __launch_bounds__(256) void scan_p3(
    const ushort* __restrict__ dt, ushort* __restrict__ u_io,
    const float* __restrict__ dbc, const float* __restrict__ A_log,
    const float* __restrict__ Dp, const ushort* __restrict__ zb,
    const float* __restrict__ Hstart) {
  __shared__ float B_s[64][16];
  __shared__ float C_s[64][16];
  const int tid = threadIdx.x;
  const int bx = blockIdx.x;
  const int db = bx & 7, c = (bx >> 3) & 31, b = bx >> 8;
  const int d = db * 256 + tid;
  const int t0 = c * 64;
  for (int i = tid; i < 1024; i += 256) {
    int t = i >> 4, s = i & 15;
    size_t bidx = ((size_t)(b * 2048 + t0 + t)) * 96;
    B_s[t][s] = dbc[bidx + 64 + s];
    C_s[t][s] = dbc[bidx + 80 + s];
  }
  float A2[16], h[16];
  const float* Arow = A_log + d * 16;
  const size_t o = ((size_t)(b * 32 + c) * 2048 + d) * 16;
#pragma unroll
  for (int s = 0; s < 16; s += 4) {
    float4 hv = *reinterpret_cast<const float4*>(&Hstart[o + s]);
    h[s] = hv.x; h[s+1] = hv.y; h[s+2] = hv.z; h[s+3] = hv.w;
  }
#pragma unroll
  for (int s = 0; s < 16; ++s) A2[s] = -__expf(Arow[s]) * 1.44269504088896f;
  const float Dval = Dp[d];
  __syncthreads();
  const size_t base = (size_t)(b * 2048 + t0) * 2048 + d;
#pragma unroll 2
  for (int t = 0; t < 64; ++t) {
    float dtv = bf2f(dt[base + (size_t)t * 2048]);
    float uv  = bf2f(u_io[base + (size_t)t * 2048]);
    float zv  = bf2f(zb[base + (size_t)t * 2048]);
    float x = dtv * uv;
    float y = 0.f;
#pragma unroll
    for (int s = 0; s < 16; ++s) {
      float e = exp2f(dtv * A2[s]);
      h[s] = e * h[s] + x * B_s[t][s];
      y += h[s] * C_s[t][s];
    }
    float yv = y + uv * Dval;
    u_io[base + (size_t)t * 2048] = f2bf(yv * zv * sigmoidf_(zv));
  }
}

extern "C" void kernel_launch(void* const* d_in, const int* in_sizes, int n_in,
                              void* d_out, int out_size, void* d_ws, size_t ws_size,
                              hipStream_t stream) {
  const float* x      = (const float*)d_in[0];
  const float* ln_g   = (const float*)d_in[1];
  const float* ln_b   = (const float*)d_in[2];
  const float* W_in   = (const float*)d_in[3];
  const float* conv_w = (const float*)d_in[4];
  const float* conv_b = (const float*)d_in[5];
  const float* W_x    = (const float*)d_in[6];
  const float* W_dt   = (const float*)d_in[7];
  const float* b_dt   = (const float*)d_in[8];
  const float* A_log  = (const float*)d_in[9];
  const float* D_par  = (const float*)d_in[10];
  const float* W_out  = (const float*)d_in[11];
  float* out = (float*)d_out;
  (void)in_sizes; (void)n_in; (void)out_size; (void)ws_size;

  char* ws = (char*)d_ws;
  size_t off = 0;
  auto alloc = [&](size_t bytes) -> void* {
    void* p = ws + off;
    off += (bytes + 255) & ~(size_t)255;
    return p;
  };
  ushort* xn    = (ushort*)alloc(4096ull * 1024 * 2);  // dead after gemm0
  ushort* Winb  = (ushort*)alloc(1024ull * 4096 * 2);  // dead after gemm0
  ushort* xbb   = (ushort*)alloc(4096ull * 2048 * 2);  // dead after conv
  ushort* zbb   = (ushort*)alloc(4096ull * 2048 * 2);
  ushort* ub    = (ushort*)alloc(4096ull * 2048 * 2);
  ushort* Wxb   = (ushort*)alloc(2048ull * 96 * 2);
  float*  dbc   = (float*) alloc(4096ull * 96 * 4);
  ushort* dtr   = (ushort*)alloc(4096ull * 64 * 2);
  ushort* Wdtb  = (ushort*)alloc(64ull * 2048 * 2);
  ushort* dtb   = (ushort*)alloc(4096ull * 2048 * 2);
  ushort* Woutb = (ushort*)alloc(2048ull * 1024 * 2);

  // chunk-scan state aliased onto dead xn/Winb region.
  float* Aprod = (float*)(ws);
  float* hEnd  = (float*)(ws + 16ull * 1024 * 1024);

  cast_bf_kernel<<<dim3(1024 * 4096 / 256), 256, 0, stream>>>(W_in, Winb, 1024 * 4096);
  cast_bf_kernel<<<dim3(2048 * 96 / 256), 256, 0, stream>>>(W_x, Wxb, 2048 * 96);
  cast_bf_kernel<<<dim3(64 * 2048 / 256), 256, 0, stream>>>(W_dt, Wdtb, 64 * 2048);
  cast_bf_kernel<<<dim3(2048 * 1024 / 256), 256, 0, stream>>>(W_out, Woutb, 2048 * 1024);

  ln_kernel<<<dim3(4096), 256, 0, stream>>>(x, ln_g, ln_b, xn);

  gemm_bf16<0><<<dim3(32, 32), 256, 0, stream>>>(xn, 1024, Winb, 4096, 1024, 4096,
                                                 nullptr, xbb, zbb, nullptr);

  conv_silu_kernel<<<dim3(8388608 / 256), 256, 0, stream>>>(xbb, conv_w, conv_b, ub);

  gemm_bf16<1><<<dim3(32, 1), 256, 0, stream>>>(ub, 2048, Wxb, 96, 2048, 96,
                                                dbc, dtr, nullptr, nullptr);

  gemm_bf16<2><<<dim3(32, 16), 256, 0, stream>>>(dtr, 64, Wdtb, 2048, 64, 2048,
                                                 nullptr, dtb, nullptr, b_dt);

  scan_p1<<<dim3(512), 256, 0, stream>>>(dtb, ub, dbc, A_log, Aprod, hEnd);
  scan_p2<<<dim3(256), 256, 0, stream>>>(Aprod, hEnd);
  scan_p3<<<dim3(512), 256, 0, stream>>>(dtb, ub, dbc, A_log, D_par, zbb, Aprod);

  gemm_bf16<3><<<dim3(32, 8), 256, 0, stream>>>(ub, 2048, Woutb, 1024, 2048, 1024,
                                                out, nullptr, nullptr, x);
}

// Round 4
// 467.330 us; speedup vs baseline: 2.0717x; 1.2979x over previous
//
#include <hip/hip_runtime.h>

#define DEV __device__ __forceinline__

typedef __attribute__((ext_vector_type(8))) short sh8;
typedef __attribute__((ext_vector_type(4))) float f32x4;

DEV ushort f2bf(float f) {
  union { float f; unsigned u; } v; v.f = f;
  unsigned r = v.u + 0x7FFFu + ((v.u >> 16) & 1u);
  return (ushort)(r >> 16);
}
DEV float bf2f(ushort h) {
  union { unsigned u; float f; } v; v.u = ((unsigned)h) << 16;
  return v.f;
}
DEV float sigmoidf_(float x) { return 1.f / (1.f + __expf(-x)); }

// async global->LDS, 16B per lane. LDS dest must be wave-uniform base.
DEV void gload16(const ushort* g, ushort* l) {
  __builtin_amdgcn_global_load_lds(
      (const __attribute__((address_space(1))) void*)g,
      (__attribute__((address_space(3))) void*)l, 16, 0, 0);
}

// ---------------- transpose-cast f32[M][N] -> bf16[N][M] ----------------
__global__ __launch_bounds__(256) void tcast_kernel(const float* __restrict__ in,
                                                    ushort* __restrict__ out, int M, int N) {
  __shared__ float tile[64][65];
  const int c0 = blockIdx.x * 64, r0 = blockIdx.y * 64;
  const int cc = threadIdx.x & 63, q = threadIdx.x >> 6;
#pragma unroll
  for (int i = 0; i < 16; ++i) {
    int rr = q + i * 4;
    int r = r0 + rr, c = c0 + cc;
    if (r < M && c < N) tile[rr][cc] = in[(size_t)r * N + c];
  }
  __syncthreads();
#pragma unroll
  for (int i = 0; i < 16; ++i) {
    int oc = q + i * 4;
    int orow = c0 + oc, ocol = r0 + cc;
    if (orow < N && ocol < M) out[(size_t)orow * M + ocol] = f2bf(tile[cc][oc]);
  }
}

// ---------------- layernorm (per token) -> bf16 ----------------
__global__ __launch_bounds__(256) void ln_kernel(const float* __restrict__ x,
    const float* __restrict__ g, const float* __restrict__ b, ushort* __restrict__ xn) {
  const int t = blockIdx.x;
  const int tid = threadIdx.x;
  const float* row = x + (size_t)t * 1024;
  float4 v = reinterpret_cast<const float4*>(row)[tid];
  float s1 = v.x + v.y + v.z + v.w;
  float s2 = v.x * v.x + v.y * v.y + v.z * v.z + v.w * v.w;
  for (int off = 32; off >= 1; off >>= 1) {
    s1 += __shfl_xor(s1, off);
    s2 += __shfl_xor(s2, off);
  }
  __shared__ float red[8];
  int w = tid >> 6, lane = tid & 63;
  if (lane == 0) { red[w] = s1; red[4 + w] = s2; }
  __syncthreads();
  s1 = red[0] + red[1] + red[2] + red[3];
  s2 = red[4] + red[5] + red[6] + red[7];
  float mu = s1 * (1.f / 1024.f);
  float var = s2 * (1.f / 1024.f) - mu * mu;
  float rstd = rsqrtf(var + 1e-5f);
  float4 gv = reinterpret_cast<const float4*>(g)[tid];
  float4 bv = reinterpret_cast<const float4*>(b)[tid];
  ushort o[4];
  o[0] = f2bf((v.x - mu) * rstd * gv.x + bv.x);
  o[1] = f2bf((v.y - mu) * rstd * gv.y + bv.y);
  o[2] = f2bf((v.z - mu) * rstd * gv.z + bv.z);
  o[3] = f2bf((v.w - mu) * rstd * gv.w + bv.w);
  *reinterpret_cast<ushort4*>(&xn[(size_t)t * 1024 + tid * 4]) = *reinterpret_cast<ushort4*>(o);
}

// ---------------- bf16 MFMA GEMM, both operands [dim][K], m97-style staging ----
// EPI 0: split C(4096) -> ob0 (n<2048) bf16, ob1 bf16
// EPI 2: ob0 = bf16(softplus(acc + aux[n]))
// EPI 3: of0 = acc + aux[m*1024+n]   (residual, f32 out)
// EPI 4: split-K partial: of0[z*M*96 + m*96 + n] = acc  (n<96)
template <int EPI>
__global__ __launch_bounds__(256)
void gemm_bt(const ushort* __restrict__ A, int lda,
             const ushort* __restrict__ Bt, int ldb,
             int K, int Nreal,
             float* __restrict__ of0,
             ushort* __restrict__ ob0, ushort* __restrict__ ob1,
             const float* __restrict__ aux) {
  __shared__ ushort As[128 * 32];
  __shared__ ushort Bs[128 * 32];
  const int tid = threadIdx.x;
  const int lane = tid & 63;
  const int w = tid >> 6;
  const int wm = w >> 1, wn = w & 1;
  const int m0 = blockIdx.x * 128;
  const int n0 = blockIdx.y * 128;
  const int row16 = lane & 15;
  const int g = lane >> 4;
  const int sr = lane >> 2;        // row within 16-row chunk
  const int sc = (lane & 3) * 8;   // col (halves)

  f32x4 acc[4][4];
#pragma unroll
  for (int i = 0; i < 4; ++i)
#pragma unroll
    for (int j = 0; j < 4; ++j) acc[i][j] = f32x4{0.f, 0.f, 0.f, 0.f};

  int kbeg = 0, kend = K;
  if (EPI == 4) { int kc = K >> 2; kbeg = blockIdx.z * kc; kend = kbeg + kc; }

  for (int kk = kbeg; kk < kend; kk += 32) {
#pragma unroll
    for (int i = 0; i < 2; ++i) {
      const int cid = i * 4 + w;          // wave-uniform chunk id (0..7)
      const int r = cid * 16 + sr;
      gload16(A  + (size_t)(m0 + r) * lda + kk + sc, &As[cid * 512]);
      gload16(Bt + (size_t)(n0 + r) * ldb + kk + sc, &Bs[cid * 512]);
    }
    __syncthreads();
    sh8 af[4], bfr[4];
#pragma unroll
    for (int i = 0; i < 4; ++i) {
      af[i]  = *reinterpret_cast<const sh8*>(&As[(wm * 64 + i * 16 + row16) * 32 + g * 8]);
      bfr[i] = *reinterpret_cast<const sh8*>(&Bs[(wn * 64 + i * 16 + row16) * 32 + g * 8]);
    }
#pragma unroll
    for (int mi = 0; mi < 4; ++mi)
#pragma unroll
      for (int ni = 0; ni < 4; ++ni)
        acc[mi][ni] = __builtin_amdgcn_mfma_f32_16x16x32_bf16(af[mi], bfr[ni], acc[mi][ni], 0, 0, 0);
    __syncthreads();
  }

#pragma unroll
  for (int mi = 0; mi < 4; ++mi) {
#pragma unroll
    for (int ni = 0; ni < 4; ++ni) {
#pragma unroll
      for (int j = 0; j < 4; ++j) {
        int m = m0 + wm * 64 + mi * 16 + g * 4 + j;
        int n = n0 + wn * 64 + ni * 16 + row16;
        float v = acc[mi][ni][j];
        if (EPI == 0) {
          ushort bvv = f2bf(v);
          if (n < 2048) ob0[(size_t)m * 2048 + n] = bvv;
          else          ob1[(size_t)m * 2048 + (n - 2048)] = bvv;
        } else if (EPI == 2) {
          float tpre = v + aux[n];
          float sp = (tpre > 20.f) ? tpre : log1pf(__expf(tpre));
          ob0[(size_t)m * 2048 + n] = f2bf(sp);
        } else if (EPI == 3) {
          of0[(size_t)m * 1024 + n] = v + aux[(size_t)m * 1024 + n];
        } else if (EPI == 4) {
          if (n < Nreal)
            of0[(size_t)blockIdx.z * 4096 * 96 + (size_t)m * 96 + n] = v;
        }
      }
    }
  }
}

// reduce split-K partials; emit dbc f32 and dtraw bf16 (n<64)
__global__ __launch_bounds__(256) void reduce_dbc(const float* __restrict__ P,
    float* __restrict__ dbc, ushort* __restrict__ dtr) {
  const int idx = blockIdx.x * 256 + threadIdx.x;   // < 4096*96
  const int STR = 4096 * 96;
  float s = P[idx] + P[idx + STR] + P[idx + 2 * STR] + P[idx + 3 * STR];
  dbc[idx] = s;
  int m = idx / 96, n = idx - m * 96;
  if (n < 64) dtr[m * 64 + n] = f2bf(s);
}

// ---------------- depthwise causal conv (width 4) + SiLU -> bf16 ----------------
__global__ __launch_bounds__(256) void conv_silu_kernel(const ushort* __restrict__ xb,
    const float* __restrict__ cw, const float* __restrict__ cb, ushort* __restrict__ u) {
  long long idx = (long long)blockIdx.x * 256 + threadIdx.x;
  int d = (int)(idx & 2047);
  int t = (int)((idx >> 11) & 2047);
  float acc = cb[d];
  float4 w4 = reinterpret_cast<const float4*>(cw)[d];
  float wj[4] = {w4.x, w4.y, w4.z, w4.w};
#pragma unroll
  for (int j = 0; j < 4; ++j) {
    int tt = t - 3 + j;
    if (tt >= 0) acc += bf2f(xb[idx + (long long)(j - 3) * 2048]) * wj[j];
  }
  u[idx] = f2bf(acc * sigmoidf_(acc));
}

// ================= chunked selective scan: 3 passes =================
__global__ __launch_bounds__(256) void scan_p1(
    const ushort* __restrict__ dt, const ushort* __restrict__ u,
    const float* __restrict__ dbc, const float* __restrict__ A_log,
    float* __restrict__ Aprod, float* __restrict__ hEnd) {
  __shared__ float B_s[64][16];
  const int tid = threadIdx.x;
  const int bx = blockIdx.x;
  const int db = bx & 7, c = (bx >> 3) & 31, b = bx >> 8;
  const int d = db * 256 + tid;
  const int t0 = c * 64;
  for (int i = tid; i < 1024; i += 256) {
    int t = i >> 4, s = i & 15;
    B_s[t][s] = dbc[((size_t)(b * 2048 + t0 + t)) * 96 + 64 + s];
  }
  float A2[16], h[16], a[16];
  const float* Arow = A_log + d * 16;
#pragma unroll
  for (int s = 0; s < 16; ++s) {
    A2[s] = -__expf(Arow[s]) * 1.44269504088896f;
    h[s] = 0.f; a[s] = 1.f;
  }
  __syncthreads();
  const size_t base = (size_t)(b * 2048 + t0) * 2048 + d;
#pragma unroll 4
  for (int t = 0; t < 64; ++t) {
    float dtv = bf2f(dt[base + (size_t)t * 2048]);
    float uv  = bf2f(u[base + (size_t)t * 2048]);
    float x = dtv * uv;
#pragma unroll
    for (int s = 0; s < 16; ++s) {
      float e = exp2f(dtv * A2[s]);
      a[s] *= e;
      h[s] = e * h[s] + x * B_s[t][s];
    }
  }
  const size_t o = ((size_t)(b * 32 + c) * 2048 + d) * 16;
#pragma unroll
  for (int s = 0; s < 16; s += 4) {
    *reinterpret_cast<float4*>(&Aprod[o + s]) = make_float4(a[s], a[s+1], a[s+2], a[s+3]);
    *reinterpret_cast<float4*>(&hEnd[o + s])  = make_float4(h[s], h[s+1], h[s+2], h[s+3]);
  }
}

__global__ __launch_bounds__(256) void scan_p2(
    float* __restrict__ Aprod, const float* __restrict__ hEnd) {
  const int i = blockIdx.x * 256 + threadIdx.x;
  const int b = i >> 15, ds = i & 32767;
  float H = 0.f;
  for (int c = 0; c < 32; ++c) {
    size_t idx = ((size_t)(b * 32 + c)) * 32768 + ds;
    float aP = Aprod[idx];
    float hE = hEnd[idx];
    Aprod[idx] = H;
    H = aP * H + hE;
  }
}

__global__ __launch_bounds__(256) void scan_p3(
    const ushort* __restrict__ dt, ushort* __restrict__ u_io,
    const float* __restrict__ dbc, const float* __restrict__ A_log,
    const float* __restrict__ Dp, const ushort* __restrict__ zb,
    const float* __restrict__ Hstart) {
  __shared__ float B_s[64][16];
  __shared__ float C_s[64][16];
  const int tid = threadIdx.x;
  const int bx = blockIdx.x;
  const int db = bx & 7, c = (bx >> 3) & 31, b = bx >> 8;
  const int d = db * 256 + tid;
  const int t0 = c * 64;
  for (int i = tid; i < 1024; i += 256) {
    int t = i >> 4, s = i & 15;
    size_t bidx = ((size_t)(b * 2048 + t0 + t)) * 96;
    B_s[t][s] = dbc[bidx + 64 + s];
    C_s[t][s] = dbc[bidx + 80 + s];
  }
  float A2[16], h[16];
  const float* Arow = A_log + d * 16;
  const size_t o = ((size_t)(b * 32 + c) * 2048 + d) * 16;
#pragma unroll
  for (int s = 0; s < 16; s += 4) {
    float4 hv = *reinterpret_cast<const float4*>(&Hstart[o + s]);
    h[s] = hv.x; h[s+1] = hv.y; h[s+2] = hv.z; h[s+3] = hv.w;
  }
#pragma unroll
  for (int s = 0; s < 16; ++s) A2[s] = -__expf(Arow[s]) * 1.44269504088896f;
  const float Dval = Dp[d];
  __syncthreads();
  const size_t base = (size_t)(b * 2048 + t0) * 2048 + d;
#pragma unroll 2
  for (int t = 0; t < 64; ++t) {
    float dtv = bf2f(dt[base + (size_t)t * 2048]);
    float uv  = bf2f(u_io[base + (size_t)t * 2048]);
    float zv  = bf2f(zb[base + (size_t)t * 2048]);
    float x = dtv * uv;
    float y = 0.f;
#pragma unroll
    for (int s = 0; s < 16; ++s) {
      float e = exp2f(dtv * A2[s]);
      h[s] = e * h[s] + x * B_s[t][s];
      y += h[s] * C_s[t][s];
    }
    float yv = y + uv * Dval;
    u_io[base + (size_t)t * 2048] = f2bf(yv * zv * sigmoidf_(zv));
  }
}

extern "C" void kernel_launch(void* const* d_in, const int* in_sizes, int n_in,
                              void* d_out, int out_size, void* d_ws, size_t ws_size,
                              hipStream_t stream) {
  const float* x      = (const float*)d_in[0];
  const float* ln_g   = (const float*)d_in[1];
  const float* ln_b   = (const float*)d_in[2];
  const float* W_in   = (const float*)d_in[3];
  const float* conv_w = (const float*)d_in[4];
  const float* conv_b = (const float*)d_in[5];
  const float* W_x    = (const float*)d_in[6];
  const float* W_dt   = (const float*)d_in[7];
  const float* b_dt   = (const float*)d_in[8];
  const float* A_log  = (const float*)d_in[9];
  const float* D_par  = (const float*)d_in[10];
  const float* W_out  = (const float*)d_in[11];
  float* out = (float*)d_out;
  (void)in_sizes; (void)n_in; (void)out_size; (void)ws_size;

  char* ws = (char*)d_ws;
  size_t off = 0;
  auto alloc = [&](size_t bytes) -> void* {
    void* p = ws + off;
    off += (bytes + 255) & ~(size_t)255;
    return p;
  };
  ushort* xn    = (ushort*)alloc(4096ull * 1024 * 2);  // dead after gemm0
  ushort* WinT  = (ushort*)alloc(4096ull * 1024 * 2);  // [4096][1024], dead after gemm0
  ushort* xbb   = (ushort*)alloc(4096ull * 2048 * 2);  // dead after conv
  ushort* zbb   = (ushort*)alloc(4096ull * 2048 * 2);
  ushort* ub    = (ushort*)alloc(4096ull * 2048 * 2);
  ushort* WxT   = (ushort*)alloc(96ull * 2048 * 2);    // [96][2048] (+128KB overread OK)
  float*  dbc   = (float*) alloc(4096ull * 96 * 4);
  ushort* dtr   = (ushort*)alloc(4096ull * 64 * 2);
  ushort* WdtT  = (ushort*)alloc(2048ull * 64 * 2);    // [2048][64]
  ushort* dtb   = (ushort*)alloc(4096ull * 2048 * 2);
  ushort* WoutT = (ushort*)alloc(1024ull * 2048 * 2);  // [1024][2048]

  // time-multiplexed scratch in the dead xn/WinT/xbb region:
  float* Pscr  = (float*)(ws);                          // 6.3 MB, live gemm1->reduce
  float* Aprod = (float*)(ws);                          // 8.4 MB, live scan_p1->p3
  float* hEnd  = (float*)(ws + 16ull * 1024 * 1024);    // 8.4 MB, live scan_p1->p2

  // weight transpose-casts: f32[M][N] -> bf16[N][M]
  tcast_kernel<<<dim3(64, 16), 256, 0, stream>>>(W_in, WinT, 1024, 4096);
  tcast_kernel<<<dim3(2, 32), 256, 0, stream>>>(W_x, WxT, 2048, 96);
  tcast_kernel<<<dim3(32, 1), 256, 0, stream>>>(W_dt, WdtT, 64, 2048);
  tcast_kernel<<<dim3(16, 32), 256, 0, stream>>>(W_out, WoutT, 2048, 1024);

  ln_kernel<<<dim3(4096), 256, 0, stream>>>(x, ln_g, ln_b, xn);

  gemm_bt<0><<<dim3(32, 32), 256, 0, stream>>>(xn, 1024, WinT, 1024, 1024, 4096,
                                               nullptr, xbb, zbb, nullptr);

  conv_silu_kernel<<<dim3(8388608 / 256), 256, 0, stream>>>(xbb, conv_w, conv_b, ub);

  gemm_bt<4><<<dim3(32, 1, 4), 256, 0, stream>>>(ub, 2048, WxT, 2048, 2048, 96,
                                                 Pscr, nullptr, nullptr, nullptr);
  reduce_dbc<<<dim3(1536), 256, 0, stream>>>(Pscr, dbc, dtr);

  gemm_bt<2><<<dim3(32, 16), 256, 0, stream>>>(dtr, 64, WdtT, 64, 64, 2048,
                                               nullptr, dtb, nullptr, b_dt);

  scan_p1<<<dim3(512), 256, 0, stream>>>(dtb, ub, dbc, A_log, Aprod, hEnd);
  scan_p2<<<dim3(256), 256, 0, stream>>>(Aprod, hEnd);
  scan_p3<<<dim3(512), 256, 0, stream>>>(dtb, ub, dbc, A_log, D_par, zbb, Aprod);

  gemm_bt<3><<<dim3(32, 8), 256, 0, stream>>>(ub, 2048, WoutT, 2048, 2048, 1024,
                                              out, nullptr, nullptr, x);
}